// Round 5
// baseline (285.196 us; speedup 1.0000x reference)
//
#include <hip/hip_runtime.h>
#include <hip/hip_bf16.h>

#define N_ROWS 8192
#define DIM    128
#define TWO_N  16384
#define CSPLIT 16
#define COLS_PER_BLOCK (TWO_N / CSPLIT)   // 1024
#define NSUB (COLS_PER_BLOCK / 16)        // 64 16-col subtiles per block
#define NBLOCKS ((TWO_N / 256) * CSPLIT)  // 1024
#define EXP_TWO 7.38905609893065f
// sqrt(2*log2(e)): H pre-scaled so dot(Hs_i,Hs_j) = 2*log2(e)*dot(h_i,h_j),
// i.e. exp(2*dot) == exp2(MFMA output) -- one v_exp_f32 per element, no muls.
#define SCALE_SQRT 1.6986430142593980f

typedef __attribute__((ext_vector_type(8))) short short8;
typedef __attribute__((ext_vector_type(4))) float float4v;

// ---------------------------------------------------------------------------
// Kernel 1: L2-normalize rows of h1,h2 (fp32), write bf16 H = s*[h1n; h2n],
// exact fp32 pos-dot per row. Also zeroes rowsum + completion counter.
// One wave per row; block = 4 waves.
// ---------------------------------------------------------------------------
__global__ __launch_bounds__(256) void norm_kernel(
    const float* __restrict__ h1, const float* __restrict__ h2,
    __hip_bfloat16* __restrict__ Hb, float* __restrict__ posdot,
    float* __restrict__ rowsum, unsigned* __restrict__ counter) {
  int tid  = threadIdx.x;
  int lane = tid & 63;
  int w    = tid >> 6;
  int row  = blockIdx.x * 4 + w;                  // 0..8191

  if (tid < 8) rowsum[blockIdx.x * 8 + tid] = 0.0f;
  if (blockIdx.x == 0 && tid == 8) *counter = 0u;

  const float2* p1 = (const float2*)(h1 + (size_t)row * DIM);
  const float2* p2 = (const float2*)(h2 + (size_t)row * DIM);
  float2 v1 = p1[lane];
  float2 v2 = p2[lane];

  float ss1 = v1.x * v1.x + v1.y * v1.y;
  float ss2 = v2.x * v2.x + v2.y * v2.y;
  #pragma unroll
  for (int m = 32; m; m >>= 1) {
    ss1 += __shfl_xor(ss1, m);
    ss2 += __shfl_xor(ss2, m);
  }
  float inv1 = 1.0f / fmaxf(sqrtf(ss1), 1e-12f);
  float inv2 = 1.0f / fmaxf(sqrtf(ss2), 1e-12f);

  float ax = v1.x * inv1, ay = v1.y * inv1;
  float bx = v2.x * inv2, by = v2.y * inv2;

  float pd = ax * bx + ay * by;   // exact (unscaled) positive-pair dot
  #pragma unroll
  for (int m = 32; m; m >>= 1) pd += __shfl_xor(pd, m);

  __hip_bfloat162* o1 = (__hip_bfloat162*)(Hb + (size_t)row * DIM);
  __hip_bfloat162* o2 = (__hip_bfloat162*)(Hb + (size_t)(row + N_ROWS) * DIM);
  __hip_bfloat162 t1, t2;
  t1.x = __float2bfloat16(ax * SCALE_SQRT); t1.y = __float2bfloat16(ay * SCALE_SQRT);
  t2.x = __float2bfloat16(bx * SCALE_SQRT); t2.y = __float2bfloat16(by * SCALE_SQRT);
  o1[lane] = t1;
  o2[lane] = t2;

  if (lane == 0) posdot[row] = pd;
}

// ---------------------------------------------------------------------------
// Kernel 2: row sums of exp2(Hs Hs^T) with NO LDS and NO barriers in the hot
// loop. A (64 rows x 128 k) is register-resident per wave; B fragments are
// loaded per 16-col subtile directly from global in MFMA fragment order
// (4 x 16 B per lane, L2/L1-resident), ping-pong prefetched one subtile ahead.
// Waves are fully independent -> memory latency hidden by ILP + 3-4 waves/SIMD,
// MFMA pipe becomes the bottleneck. (R4 post-mortem: LDS + syncthreads kept
// both pipes at 17% — the vmcnt(0)+barrier drain was ~2/3 of the runtime.)
// launch_bounds(256,2): do NOT tighten — (256,4)'s 128-reg cap spilled (R3).
// ---------------------------------------------------------------------------
__global__ __launch_bounds__(256, 2) void ntx_main(
    const __hip_bfloat16* __restrict__ Hb, float* __restrict__ rowsum,
    const float* __restrict__ posdot, unsigned* __restrict__ counter,
    float* __restrict__ out) {
  const short* H = (const short*)Hb;

  int tid  = threadIdx.x;
  int lane = tid & 63;
  int w    = tid >> 6;
  int q    = lane >> 4;     // k-chunk selector within fragment
  int m    = lane & 15;     // row/col within 16-subtile

  int rowbase = blockIdx.x * 256 + w * 64;
  int colbase = blockIdx.y * COLS_PER_BLOCK;

  // A fragments: 4 row-subtiles x 4 k-steps, resident for the whole kernel.
  short8 a[4][4];
  #pragma unroll
  for (int r = 0; r < 4; ++r)
    #pragma unroll
    for (int s = 0; s < 4; ++s)
      a[r][s] = *(const short8*)(H + (size_t)(rowbase + r * 16 + m) * DIM + s * 32 + q * 8);

  float rowacc[4][4];
  #pragma unroll
  for (int r = 0; r < 4; ++r)
    #pragma unroll
    for (int i = 0; i < 4; ++i) rowacc[r][i] = 0.0f;

  // B fragment base for this lane: col = colbase + m, k base = q*8.
  // Subtile c advances col by 16 -> +16*DIM shorts.
  const short* bbase = H + (size_t)(colbase + m) * DIM + q * 8;

  short8 b0[4], b1[4];
  #pragma unroll
  for (int s = 0; s < 4; ++s) b0[s] = *(const short8*)(bbase + s * 32);

  #define COMPUTE(BARR)                                                     \
    do {                                                                    \
      _Pragma("unroll")                                                     \
      for (int r = 0; r < 4; ++r) {                                         \
        float4v acc = {0.f, 0.f, 0.f, 0.f};                                 \
        _Pragma("unroll")                                                   \
        for (int s = 0; s < 4; ++s)                                         \
          acc = __builtin_amdgcn_mfma_f32_16x16x32_bf16(a[r][s], BARR[s],   \
                                                        acc, 0, 0, 0);      \
        _Pragma("unroll")                                                   \
        for (int i = 0; i < 4; ++i)                                         \
          rowacc[r][i] += __builtin_amdgcn_exp2f(acc[i]);                   \
      }                                                                     \
    } while (0)

  // Ping-pong over 64 subtiles, 2 per iteration; prefetch one subtile ahead.
  for (int c = 0; c < NSUB; c += 2) {
    const short* nb1 = bbase + (size_t)(c + 1) * 16 * DIM;
    #pragma unroll
    for (int s = 0; s < 4; ++s) b1[s] = *(const short8*)(nb1 + s * 32);
    COMPUTE(b0);
    int c2 = (c + 2 < NSUB) ? (c + 2) : (NSUB - 1);   // clamp: avoid OOB read
    const short* nb0 = bbase + (size_t)c2 * 16 * DIM;
    #pragma unroll
    for (int s = 0; s < 4; ++s) b0[s] = *(const short8*)(nb0 + s * 32);
    COMPUTE(b1);
  }
  #undef COMPUTE

  // Reduce across the 16 column-lanes holding the same rows, then atomicAdd.
  #pragma unroll
  for (int r = 0; r < 4; ++r)
    #pragma unroll
    for (int i = 0; i < 4; ++i) {
      float v = rowacc[r][i];
      v += __shfl_xor(v, 1);
      v += __shfl_xor(v, 2);
      v += __shfl_xor(v, 4);
      v += __shfl_xor(v, 8);
      rowacc[r][i] = v;
    }
  if (m == 0) {
    #pragma unroll
    for (int r = 0; r < 4; ++r)
      #pragma unroll
      for (int i = 0; i < 4; ++i)
        atomicAdd(&rowsum[rowbase + r * 16 + q * 4 + i], rowacc[r][i]);
  }

  // ---- completion-counter finalize (last block computes the loss) ----
  __shared__ float smemf[8];
  __shared__ unsigned is_last;
  __threadfence();          // release our rowsum atomics
  __syncthreads();
  if (tid == 0) {
    unsigned old = atomicAdd(counter, 1u);
    is_last = (old == NBLOCKS - 1) ? 1u : 0u;
  }
  __syncthreads();
  if (is_last) {
    __threadfence();        // acquire all blocks' rowsum atomics
    float ld = 0.0f, pp = 0.0f;
    for (int i = tid; i < TWO_N; i += 256) {
      float v = __hip_atomic_load(&rowsum[i], __ATOMIC_RELAXED, __HIP_MEMORY_SCOPE_AGENT);
      ld += __logf(v - EXP_TWO);
    }
    for (int i = tid; i < N_ROWS; i += 256) pp += posdot[i];
    #pragma unroll
    for (int mm = 32; mm; mm >>= 1) {
      ld += __shfl_xor(ld, mm);
      pp += __shfl_xor(pp, mm);
    }
    if (lane == 0) { smemf[w] = ld; smemf[4 + w] = pp; }
    __syncthreads();
    if (tid == 0) {
      float tl = smemf[0] + smemf[1] + smemf[2] + smemf[3];
      float tp = smemf[4] + smemf[5] + smemf[6] + smemf[7];
      *out = (tl - 4.0f * tp) / (float)TWO_N;
    }
  }
}

extern "C" void kernel_launch(void* const* d_in, const int* in_sizes, int n_in,
                              void* d_out, int out_size, void* d_ws, size_t ws_size,
                              hipStream_t stream) {
  const float* h1 = (const float*)d_in[0];
  const float* h2 = (const float*)d_in[1];
  char* ws = (char*)d_ws;

  __hip_bfloat16* Hb = (__hip_bfloat16*)ws;                       // 4 MB
  float* rowsum      = (float*)(ws + 4194304);                    // 64 KB
  float* posdot      = (float*)(ws + 4194304 + 65536);            // 32 KB
  unsigned* counter  = (unsigned*)(ws + 4194304 + 65536 + 32768); // 4 B
  float* out         = (float*)d_out;

  norm_kernel<<<N_ROWS / 4, 256, 0, stream>>>(h1, h2, Hb, posdot, rowsum, counter);
  ntx_main<<<dim3(TWO_N / 256, CSPLIT), 256, 0, stream>>>(Hb, rowsum, posdot, counter, out);
}

// Round 6
// 221.789 us; speedup vs baseline: 1.2859x; 1.2859x over previous
//
#include <hip/hip_runtime.h>
#include <hip/hip_bf16.h>

#define N_ROWS 8192
#define DIM    128
#define TWO_N  16384
#define CSPLIT 16
#define COLS_PER_BLOCK (TWO_N / CSPLIT)   // 1024
#define NSUB (COLS_PER_BLOCK / 16)        // 64 16-col subtiles per block
#define NBLOCKS ((TWO_N / 256) * CSPLIT)  // 1024
#define EXP_TWO 7.38905609893065f
// sqrt(2*log2(e)): H pre-scaled so dot(Hs_i,Hs_j) = 2*log2(e)*dot(h_i,h_j),
// i.e. exp(2*dot) == exp2(MFMA output) -- one v_exp_f32 per element, no muls.
#define SCALE_SQRT 1.6986430142593980f

typedef __attribute__((ext_vector_type(8))) short short8;
typedef __attribute__((ext_vector_type(4))) float float4v;

// ---------------------------------------------------------------------------
// Hfrag layout: H stored in MFMA-fragment order so ntx_main's loads are
// perfectly coalesced (lane*16B contiguous). Chunk (ct, s, lane) holds
// H[row = ct*16 + (lane&15)][k = s*32 + (lane>>4)*8 ... +8] as 8 bf16.
// Short offset = (ct*4 + s)*512 + lane*8. A and B fragments use the SAME
// per-lane mapping (verified: R1-R5 passed with identical a/b gathers).
// ---------------------------------------------------------------------------

// ---------------------------------------------------------------------------
// Kernel 1: L2-normalize rows of h1,h2 (fp32), write bf16 Hfrag = s*[h1n; h2n]
// in fragment order; exact fp32 pos-dot per row; zero rowsum + counter.
// One wave per row; block = 4 waves. Stores are 4B scattered (16x16B segments
// per wave) -- one-time 4 MB write, acceptable.
// ---------------------------------------------------------------------------
__global__ __launch_bounds__(256) void norm_kernel(
    const float* __restrict__ h1, const float* __restrict__ h2,
    short* __restrict__ Hf, float* __restrict__ posdot,
    float* __restrict__ rowsum, unsigned* __restrict__ counter) {
  int tid  = threadIdx.x;
  int lane = tid & 63;
  int w    = tid >> 6;
  int row  = blockIdx.x * 4 + w;                  // 0..8191

  if (tid < 8) rowsum[blockIdx.x * 8 + tid] = 0.0f;
  if (blockIdx.x == 0 && tid == 8) *counter = 0u;

  const float2* p1 = (const float2*)(h1 + (size_t)row * DIM);
  const float2* p2 = (const float2*)(h2 + (size_t)row * DIM);
  float2 v1 = p1[lane];
  float2 v2 = p2[lane];

  float ss1 = v1.x * v1.x + v1.y * v1.y;
  float ss2 = v2.x * v2.x + v2.y * v2.y;
  #pragma unroll
  for (int m = 32; m; m >>= 1) {
    ss1 += __shfl_xor(ss1, m);
    ss2 += __shfl_xor(ss2, m);
  }
  float inv1 = 1.0f / fmaxf(sqrtf(ss1), 1e-12f);
  float inv2 = 1.0f / fmaxf(sqrtf(ss2), 1e-12f);

  float ax = v1.x * inv1, ay = v1.y * inv1;
  float bx = v2.x * inv2, by = v2.y * inv2;

  float pd = ax * bx + ay * by;   // exact (unscaled) positive-pair dot
  #pragma unroll
  for (int m = 32; m; m >>= 1) pd += __shfl_xor(pd, m);

  // fragment-order address for this lane's 2 shorts (k = 2*lane, 2*lane+1)
  int s  = lane >> 4;           // k-step (k>>5)
  int qq = (lane >> 2) & 3;     // quad  ((k>>3)&3)
  int jo = (lane & 3) * 2;      // short offset within the 8-short chunk
  int row2 = row + N_ROWS;
  size_t off1 = ((size_t)(row  >> 4) * 4 + s) * 512 + (qq * 16 + (row  & 15)) * 8 + jo;
  size_t off2 = ((size_t)(row2 >> 4) * 4 + s) * 512 + (qq * 16 + (row2 & 15)) * 8 + jo;

  __hip_bfloat162 t1, t2;
  t1.x = __float2bfloat16(ax * SCALE_SQRT); t1.y = __float2bfloat16(ay * SCALE_SQRT);
  t2.x = __float2bfloat16(bx * SCALE_SQRT); t2.y = __float2bfloat16(by * SCALE_SQRT);
  *(__hip_bfloat162*)(Hf + off1) = t1;
  *(__hip_bfloat162*)(Hf + off2) = t2;

  if (lane == 0) posdot[row] = pd;
}

// ---------------------------------------------------------------------------
// Kernel 2: row sums of exp2(Hs Hs^T). No LDS, no hot-loop barriers.
// A (64 rows x 128 k) register-resident per wave; B streamed from Hfrag with
// perfectly-coalesced 1KB loads (lane*16B), distance-2 software pipeline
// (4 buffer sets). All 4 waves of a block read the same B stream -> L1 reuse.
// R5 post-mortem: fragment gather from row-major H was a 16-segment scatter;
// fragment-ordered storage makes every load single-segment.
// launch_bounds(256,2): (256,4)'s 128-reg cap spilled catastrophically (R3).
// ---------------------------------------------------------------------------
__global__ __launch_bounds__(256, 2) void ntx_main(
    const short* __restrict__ Hf, float* __restrict__ rowsum,
    const float* __restrict__ posdot, unsigned* __restrict__ counter,
    float* __restrict__ out) {
  int tid  = threadIdx.x;
  int lane = tid & 63;
  int w    = tid >> 6;
  int q    = lane >> 4;
  int m    = lane & 15;

  int rowbase = blockIdx.x * 256 + w * 64;
  int colbase = blockIdx.y * COLS_PER_BLOCK;

  // A fragments: 4 row-subtiles x 4 k-steps; subtile stride = 2048 shorts.
  const short* Abase = Hf + (size_t)(rowbase >> 4) * 2048 + lane * 8;
  short8 a[4][4];
  #pragma unroll
  for (int r = 0; r < 4; ++r)
    #pragma unroll
    for (int s = 0; s < 4; ++s)
      a[r][s] = *(const short8*)(Abase + (r * 4 + s) * 512);

  float rowacc[4][4];
  #pragma unroll
  for (int r = 0; r < 4; ++r)
    #pragma unroll
    for (int i = 0; i < 4; ++i) rowacc[r][i] = 0.0f;

  const short* Bbase = Hf + (size_t)(colbase >> 4) * 2048 + lane * 8;

  short8 b0[4], b1[4], b2[4], b3[4];

  #define LOADB(DST, CIDX)                                                  \
    do {                                                                    \
      _Pragma("unroll")                                                     \
      for (int s = 0; s < 4; ++s)                                           \
        DST[s] = *(const short8*)(Bbase + ((size_t)(CIDX) * 4 + s) * 512);  \
    } while (0)

  #define COMPUTE(BARR)                                                     \
    do {                                                                    \
      _Pragma("unroll")                                                     \
      for (int r = 0; r < 4; ++r) {                                         \
        float4v acc = {0.f, 0.f, 0.f, 0.f};                                 \
        _Pragma("unroll")                                                   \
        for (int s = 0; s < 4; ++s)                                         \
          acc = __builtin_amdgcn_mfma_f32_16x16x32_bf16(a[r][s], BARR[s],   \
                                                        acc, 0, 0, 0);      \
        _Pragma("unroll")                                                   \
        for (int i = 0; i < 4; ++i)                                         \
          rowacc[r][i] += __builtin_amdgcn_exp2f(acc[i]);                   \
      }                                                                     \
    } while (0)

  LOADB(b0, 0);
  LOADB(b1, 1);
  for (int c = 0; c < NSUB; c += 4) {
    LOADB(b2, c + 2);           // NSUB%4==0: c+3 <= NSUB-1 always
    LOADB(b3, c + 3);
    COMPUTE(b0);
    COMPUTE(b1);
    int c4 = (c + 4 < NSUB) ? c + 4 : 0;   // harmless dummy reload on last iter
    int c5 = (c + 5 < NSUB) ? c + 5 : 0;
    LOADB(b0, c4);
    LOADB(b1, c5);
    COMPUTE(b2);
    COMPUTE(b3);
  }
  #undef LOADB
  #undef COMPUTE

  // Reduce across the 16 column-lanes holding the same rows, then atomicAdd.
  #pragma unroll
  for (int r = 0; r < 4; ++r)
    #pragma unroll
    for (int i = 0; i < 4; ++i) {
      float v = rowacc[r][i];
      v += __shfl_xor(v, 1);
      v += __shfl_xor(v, 2);
      v += __shfl_xor(v, 4);
      v += __shfl_xor(v, 8);
      rowacc[r][i] = v;
    }
  if (m == 0) {
    #pragma unroll
    for (int r = 0; r < 4; ++r)
      #pragma unroll
      for (int i = 0; i < 4; ++i)
        atomicAdd(&rowsum[rowbase + r * 16 + q * 4 + i], rowacc[r][i]);
  }

  // ---- completion-counter finalize (last block computes the loss) ----
  __shared__ float smemf[8];
  __shared__ unsigned is_last;
  __threadfence();          // release our rowsum atomics
  __syncthreads();
  if (tid == 0) {
    unsigned old = atomicAdd(counter, 1u);
    is_last = (old == NBLOCKS - 1) ? 1u : 0u;
  }
  __syncthreads();
  if (is_last) {
    __threadfence();        // acquire all blocks' rowsum atomics
    float ld = 0.0f, pp = 0.0f;
    for (int i = tid; i < TWO_N; i += 256) {
      float v = __hip_atomic_load(&rowsum[i], __ATOMIC_RELAXED, __HIP_MEMORY_SCOPE_AGENT);
      ld += __logf(v - EXP_TWO);
    }
    for (int i = tid; i < N_ROWS; i += 256) pp += posdot[i];
    #pragma unroll
    for (int mm = 32; mm; mm >>= 1) {
      ld += __shfl_xor(ld, mm);
      pp += __shfl_xor(pp, mm);
    }
    if (lane == 0) { smemf[w] = ld; smemf[4 + w] = pp; }
    __syncthreads();
    if (tid == 0) {
      float tl = smemf[0] + smemf[1] + smemf[2] + smemf[3];
      float tp = smemf[4] + smemf[5] + smemf[6] + smemf[7];
      *out = (tl - 4.0f * tp) / (float)TWO_N;
    }
  }
}

extern "C" void kernel_launch(void* const* d_in, const int* in_sizes, int n_in,
                              void* d_out, int out_size, void* d_ws, size_t ws_size,
                              hipStream_t stream) {
  const float* h1 = (const float*)d_in[0];
  const float* h2 = (const float*)d_in[1];
  char* ws = (char*)d_ws;

  short* Hf         = (short*)ws;                                 // 4 MB (fragment order)
  float* rowsum     = (float*)(ws + 4194304);                     // 64 KB
  float* posdot     = (float*)(ws + 4194304 + 65536);             // 32 KB
  unsigned* counter = (unsigned*)(ws + 4194304 + 65536 + 32768);  // 4 B
  float* out        = (float*)d_out;

  norm_kernel<<<N_ROWS / 4, 256, 0, stream>>>(h1, h2, Hf, posdot, rowsum, counter);
  ntx_main<<<dim3(TWO_N / 256, CSPLIT), 256, 0, stream>>>(Hf, rowsum, posdot, counter, out);
}